// Round 2
// baseline (8609.982 us; speedup 1.0000x reference)
//
#include <hip/hip_runtime.h>
#include <hip/hip_bf16.h>
#include <math.h>

// ---- problem constants ----
#define D_  768
#define T_  1024
#define B_  2
#define H_  12
#define HD_ 64
#define L_  8
#define F_  3072
#define V_  1024
#define M_  (B_ * T_)   // 2048 rows of activations

typedef __bf16 bf16_t;
typedef __bf16 bf16x8 __attribute__((ext_vector_type(8)));
typedef float  f32x4  __attribute__((ext_vector_type(4)));

// ---------------- embed: x = tok_emb[ids] + pos_emb (all f32) ----------------
__global__ __launch_bounds__(256) void embed_kernel(
    const int* __restrict__ ids, const float* __restrict__ tok,
    const float* __restrict__ pos, float* __restrict__ x)
{
    const int row = blockIdx.x;          // b*T + t
    const int t   = row & (T_ - 1);
    const int id  = ids[row];
    const int c   = threadIdx.x;
#pragma unroll
    for (int i = 0; i < 3; ++i) {
        const int d = c + i * 256;
        x[(size_t)row * D_ + d] = tok[(size_t)id * D_ + d] + pos[(size_t)t * D_ + d];
    }
}

// ---------------- layernorm: f32 in -> bf16 out (feeds bf16 GEMM A) ----------------
__device__ __forceinline__ float block_sum(float v)
{
    __shared__ float sm[4];
#pragma unroll
    for (int off = 32; off; off >>= 1) v += __shfl_down(v, off);
    if ((threadIdx.x & 63) == 0) sm[threadIdx.x >> 6] = v;
    __syncthreads();
    const float r = sm[0] + sm[1] + sm[2] + sm[3];
    __syncthreads();   // protect sm for next call
    return r;
}

__global__ __launch_bounds__(256) void ln_kernel(
    const float* __restrict__ x, const float* __restrict__ w,
    const float* __restrict__ b, bf16_t* __restrict__ out)
{
    const int row = blockIdx.x;
    const float* xr = x + (size_t)row * D_;
    const int t = threadIdx.x;
    const float v0 = xr[t];
    const float v1 = xr[t + 256];
    const float v2 = xr[t + 512];
    const float mu = block_sum(v0 + v1 + v2) * (1.f / D_);
    const float d0 = v0 - mu, d1 = v1 - mu, d2 = v2 - mu;
    const float var = block_sum(d0 * d0 + d1 * d1 + d2 * d2) * (1.f / D_);
    const float rstd = rsqrtf(var + 1e-5f);
    bf16_t* o = out + (size_t)row * D_;
    o[t]       = (bf16_t)(d0 * rstd * w[t]       + b[t]);
    o[t + 256] = (bf16_t)(d1 * rstd * w[t + 256] + b[t + 256]);
    o[t + 512] = (bf16_t)(d2 * rstd * w[t + 512] + b[t + 512]);
}

// ---------------- GEMM: C[M,N] = act(A_bf16[M,K] @ B_f32 + bias + res) ----------------
// B converted f32->bf16 at LDS stage-in; accumulate f32.
// BT=false: B stored [K][N] (weights). BT=true: B stored [N][K] (tied lm_head).
// 64x64 block tile, BK=32, 4 waves, each wave a 16x64 stripe, mfma_f32_16x16x32_bf16.
// Layouts (learn_hip m89/m91): A frag m=lane&15,k=quad*8+j; B frag n=lane&15,k=quad*8+j;
// D: row=quad*4+reg, col=lane&15.
template<bool BT, bool RES, bool BIAS, bool GELU_, bool OUTF32>
__global__ __launch_bounds__(256) void gemm_kernel(
    const bf16_t* __restrict__ A, const float* __restrict__ B,
    const float* __restrict__ bias, const float* __restrict__ res,
    void* __restrict__ Cp, int M, int N, int K)
{
    __shared__ bf16_t As[64][40];   // [m][k], pad 40 keeps 16B align + breaks pow2 stride
    __shared__ bf16_t Bs[64][40];   // [n][k]

    const int t    = threadIdx.x;
    const int bn0  = blockIdx.x * 64;
    const int bm0  = blockIdx.y * 64;
    const int wave = t >> 6;
    const int lane = t & 63;
    const int lr   = lane & 15;
    const int quad = lane >> 4;

    f32x4 acc[4];
#pragma unroll
    for (int i = 0; i < 4; ++i) { f32x4 z = {0.f, 0.f, 0.f, 0.f}; acc[i] = z; }

    // staging maps
    const int ar = t >> 2;            // 0..63 (A row / BT-B row n)
    const int ak = (t & 3) << 3;      // 0,8,16,24
    const bf16_t* Ap = A + (size_t)(bm0 + ar) * K + ak;
    const int bk  = t >> 3;           // 0..31
    const int bnn = (t & 7) << 3;     // 0..56
    const float* Bp = BT ? (B + (size_t)(bn0 + ar) * K + ak)
                         : (B + (size_t)bk * N + bn0 + bnn);

    for (int k0 = 0; k0 < K; k0 += 32) {
        __syncthreads();
        bf16x8 av = *(const bf16x8*)(Ap + k0);
        *(bf16x8*)(&As[ar][ak]) = av;
        if (BT) {
            f32x4 b0 = *(const f32x4*)(Bp + k0);
            f32x4 b1 = *(const f32x4*)(Bp + k0 + 4);
            bf16x8 bv;
#pragma unroll
            for (int i = 0; i < 4; ++i) { bv[i] = (bf16_t)b0[i]; bv[4 + i] = (bf16_t)b1[i]; }
            *(bf16x8*)(&Bs[ar][ak]) = bv;
        } else {
            f32x4 b0 = *(const f32x4*)(Bp + (size_t)k0 * N);
            f32x4 b1 = *(const f32x4*)(Bp + (size_t)k0 * N + 4);
#pragma unroll
            for (int i = 0; i < 4; ++i) {
                Bs[bnn + i][bk]     = (bf16_t)b0[i];
                Bs[bnn + 4 + i][bk] = (bf16_t)b1[i];
            }
        }
        __syncthreads();

        bf16x8 af = *(const bf16x8*)(&As[wave * 16 + lr][quad * 8]);
#pragma unroll
        for (int nt = 0; nt < 4; ++nt) {
            bf16x8 bfrag = *(const bf16x8*)(&Bs[nt * 16 + lr][quad * 8]);
            acc[nt] = __builtin_amdgcn_mfma_f32_16x16x32_bf16(af, bfrag, acc[nt], 0, 0, 0);
        }
    }

    const int mb = bm0 + wave * 16 + quad * 4;
#pragma unroll
    for (int nt = 0; nt < 4; ++nt) {
        const int n = bn0 + nt * 16 + lr;
        const float bv = BIAS ? bias[n] : 0.f;
#pragma unroll
        for (int r = 0; r < 4; ++r) {
            const int m = mb + r;
            float v = acc[nt][r] + bv;
            if (RES)   v += res[(size_t)m * N + n];
            if (GELU_) v = 0.5f * v * (1.f + erff(v * 0.70710678118654752f));
            if (OUTF32) ((float*)Cp)[(size_t)m * N + n] = v;
            else        ((bf16_t*)Cp)[(size_t)m * N + n] = (bf16_t)v;
        }
    }
}

// ---------------- attention (online softmax, 1 block per (b,h,q)) ----------------
// qkv row layout (bf16): [b*T+t][0:768)=Q, [768:1536)=K, [1536:2304)=V; head h at h*64+d.
__global__ __launch_bounds__(256) void attn_kernel(
    const bf16_t* __restrict__ qkv, bf16_t* __restrict__ y)
{
    const int q    = blockIdx.x;
    const int bh   = blockIdx.y;             // h + H*b
    const int b    = bh / H_;
    const int hh   = bh % H_;
    const int lane = threadIdx.x & 63;
    const int wave = threadIdx.x >> 6;
    const int col  = hh * HD_ + lane;

    const size_t rowQ = ((size_t)b * T_ + q) * (3 * D_);
    const float qd = (float)qkv[rowQ + col] * 0.125f;   // fold 1/sqrt(64)

    float m = -1e30f, l = 0.f, o = 0.f;
    for (int k = wave; k <= q; k += 4) {
        const size_t rowK = ((size_t)b * T_ + k) * (3 * D_);
        float p = qd * (float)qkv[rowK + D_ + col];
#pragma unroll
        for (int off = 32; off; off >>= 1) p += __shfl_xor(p, off);
        const float nm    = fmaxf(m, p);
        const float alpha = __expf(m - nm);
        const float w     = __expf(p - nm);
        const float vd    = (float)qkv[rowK + 2 * D_ + col];
        l = l * alpha + w;
        o = o * alpha + w * vd;
        m = nm;
    }

    __shared__ float sm[4], sl[4], so[4][64];
    if (lane == 0) { sm[wave] = m; sl[wave] = l; }
    so[wave][lane] = o;
    __syncthreads();
    if (wave == 0) {
        const float M = fmaxf(fmaxf(sm[0], sm[1]), fmaxf(sm[2], sm[3]));
        const float e0 = __expf(sm[0] - M), e1 = __expf(sm[1] - M);
        const float e2 = __expf(sm[2] - M), e3 = __expf(sm[3] - M);
        const float L = sl[0] * e0 + sl[1] * e1 + sl[2] * e2 + sl[3] * e3;
        const float O = (so[0][lane] * e0 + so[1][lane] * e1 +
                         so[2][lane] * e2 + so[3][lane] * e3) / L;
        y[((size_t)b * T_ + q) * D_ + col] = (bf16_t)O;
    }
}

// ---------------- launch ----------------
extern "C" void kernel_launch(void* const* d_in, const int* in_sizes, int n_in,
                              void* d_out, int out_size, void* d_ws, size_t ws_size,
                              hipStream_t stream)
{
    const int*   ids  = (const int*)d_in[0];
    const float* tok  = (const float*)d_in[1];
    const float* pos  = (const float*)d_in[2];
    const float* l1w  = (const float*)d_in[3];
    const float* l1b  = (const float*)d_in[4];
    const float* qkvw = (const float*)d_in[5];
    const float* outw = (const float*)d_in[6];
    const float* l2w  = (const float*)d_in[7];
    const float* l2b  = (const float*)d_in[8];
    const float* w1   = (const float*)d_in[9];
    const float* b1   = (const float*)d_in[10];
    const float* w2   = (const float*)d_in[11];
    const float* b2   = (const float*)d_in[12];
    const float* lnfw = (const float*)d_in[13];
    const float* lnfb = (const float*)d_in[14];

    // ws layout: residual x in f32 (precision), activations bf16 (GEMM inputs)
    float*  x   = (float*)d_ws;                         // [2048][768]  f32
    bf16_t* h   = (bf16_t*)(x + (size_t)M_ * D_);       // [2048][768]  bf16
    bf16_t* qkv = h   + (size_t)M_ * D_;                // [2048][2304] bf16
    bf16_t* y   = qkv + (size_t)M_ * 3 * D_;            // [2048][768]  bf16
    bf16_t* mid = y   + (size_t)M_ * D_;                // [2048][3072] bf16

    embed_kernel<<<M_, 256, 0, stream>>>(ids, tok, pos, x);

    for (int l = 0; l < L_; ++l) {
        ln_kernel<<<M_, 256, 0, stream>>>(x, l1w + l * D_, l1b + l * D_, h);
        gemm_kernel<false, false, false, false, false><<<dim3(3 * D_ / 64, M_ / 64), 256, 0, stream>>>(
            h, qkvw + (size_t)l * D_ * 3 * D_, nullptr, nullptr, qkv, M_, 3 * D_, D_);
        attn_kernel<<<dim3(T_, B_ * H_), 256, 0, stream>>>(qkv, y);
        gemm_kernel<false, true, false, false, true><<<dim3(D_ / 64, M_ / 64), 256, 0, stream>>>(
            y, outw + (size_t)l * D_ * D_, nullptr, x, x, M_, D_, D_);
        ln_kernel<<<M_, 256, 0, stream>>>(x, l2w + l * D_, l2b + l * D_, h);
        gemm_kernel<false, false, true, true, false><<<dim3(F_ / 64, M_ / 64), 256, 0, stream>>>(
            h, w1 + (size_t)l * D_ * F_, b1 + (size_t)l * F_, nullptr, mid, M_, F_, D_);
        gemm_kernel<false, true, true, false, true><<<dim3(D_ / 64, M_ / 64), 256, 0, stream>>>(
            mid, w2 + (size_t)l * F_ * D_, b2 + (size_t)l * D_, x, x, M_, D_, F_);
    }

    ln_kernel<<<M_, 256, 0, stream>>>(x, lnfw, lnfb, h);
    // lm_head: logits = h @ tok_emb^T (tok [V][D] = [N][K] -> BT path), f32 out
    gemm_kernel<true, false, false, false, true><<<dim3(V_ / 64, M_ / 64), 256, 0, stream>>>(
        h, tok, nullptr, nullptr, d_out, M_, V_, D_);
}

// Round 3
// 2260.029 us; speedup vs baseline: 3.8097x; 3.8097x over previous
//
#include <hip/hip_runtime.h>
#include <hip/hip_bf16.h>
#include <math.h>

// ---- problem constants ----
#define D_  768
#define T_  1024
#define B_  2
#define H_  12
#define HD_ 64
#define L_  8
#define F_  3072
#define V_  1024
#define M_  (B_ * T_)   // 2048 rows of activations

typedef __bf16 bf16_t;
typedef __bf16 bf16x8 __attribute__((ext_vector_type(8)));
typedef float  f32x4  __attribute__((ext_vector_type(4)));

// ---------------- embed: x = tok_emb[ids] + pos_emb (all f32) ----------------
__global__ __launch_bounds__(256) void embed_kernel(
    const int* __restrict__ ids, const float* __restrict__ tok,
    const float* __restrict__ pos, float* __restrict__ x)
{
    const int row = blockIdx.x;          // b*T + t
    const int t   = row & (T_ - 1);
    const int id  = ids[row];
    const int c   = threadIdx.x;
#pragma unroll
    for (int i = 0; i < 3; ++i) {
        const int d = c + i * 256;
        x[(size_t)row * D_ + d] = tok[(size_t)id * D_ + d] + pos[(size_t)t * D_ + d];
    }
}

// ---------------- layernorm: f32 in -> bf16 out (feeds bf16 GEMM A) ----------------
__device__ __forceinline__ float block_sum(float v)
{
    __shared__ float sm[4];
#pragma unroll
    for (int off = 32; off; off >>= 1) v += __shfl_down(v, off);
    if ((threadIdx.x & 63) == 0) sm[threadIdx.x >> 6] = v;
    __syncthreads();
    const float r = sm[0] + sm[1] + sm[2] + sm[3];
    __syncthreads();   // protect sm for next call
    return r;
}

__global__ __launch_bounds__(256) void ln_kernel(
    const float* __restrict__ x, const float* __restrict__ w,
    const float* __restrict__ b, bf16_t* __restrict__ out)
{
    const int row = blockIdx.x;
    const float* xr = x + (size_t)row * D_;
    const int t = threadIdx.x;
    const float v0 = xr[t];
    const float v1 = xr[t + 256];
    const float v2 = xr[t + 512];
    const float mu = block_sum(v0 + v1 + v2) * (1.f / D_);
    const float d0 = v0 - mu, d1 = v1 - mu, d2 = v2 - mu;
    const float var = block_sum(d0 * d0 + d1 * d1 + d2 * d2) * (1.f / D_);
    const float rstd = rsqrtf(var + 1e-5f);
    bf16_t* o = out + (size_t)row * D_;
    o[t]       = (bf16_t)(d0 * rstd * w[t]       + b[t]);
    o[t + 256] = (bf16_t)(d1 * rstd * w[t + 256] + b[t + 256]);
    o[t + 512] = (bf16_t)(d2 * rstd * w[t + 512] + b[t + 512]);
}

// ---------------- GEMM: C[M,N] = act(A_bf16[M,K] @ B_f32 + bias + res) ----------------
// (unchanged from round 2 — passed)
template<bool BT, bool RES, bool BIAS, bool GELU_, bool OUTF32>
__global__ __launch_bounds__(256) void gemm_kernel(
    const bf16_t* __restrict__ A, const float* __restrict__ B,
    const float* __restrict__ bias, const float* __restrict__ res,
    void* __restrict__ Cp, int M, int N, int K)
{
    __shared__ bf16_t As[64][40];
    __shared__ bf16_t Bs[64][40];

    const int t    = threadIdx.x;
    const int bn0  = blockIdx.x * 64;
    const int bm0  = blockIdx.y * 64;
    const int wave = t >> 6;
    const int lane = t & 63;
    const int lr   = lane & 15;
    const int quad = lane >> 4;

    f32x4 acc[4];
#pragma unroll
    for (int i = 0; i < 4; ++i) { f32x4 z = {0.f, 0.f, 0.f, 0.f}; acc[i] = z; }

    const int ar = t >> 2;
    const int ak = (t & 3) << 3;
    const bf16_t* Ap = A + (size_t)(bm0 + ar) * K + ak;
    const int bk  = t >> 3;
    const int bnn = (t & 7) << 3;
    const float* Bp = BT ? (B + (size_t)(bn0 + ar) * K + ak)
                         : (B + (size_t)bk * N + bn0 + bnn);

    for (int k0 = 0; k0 < K; k0 += 32) {
        __syncthreads();
        bf16x8 av = *(const bf16x8*)(Ap + k0);
        *(bf16x8*)(&As[ar][ak]) = av;
        if (BT) {
            f32x4 b0 = *(const f32x4*)(Bp + k0);
            f32x4 b1 = *(const f32x4*)(Bp + k0 + 4);
            bf16x8 bv;
#pragma unroll
            for (int i = 0; i < 4; ++i) { bv[i] = (bf16_t)b0[i]; bv[4 + i] = (bf16_t)b1[i]; }
            *(bf16x8*)(&Bs[ar][ak]) = bv;
        } else {
            f32x4 b0 = *(const f32x4*)(Bp + (size_t)k0 * N);
            f32x4 b1 = *(const f32x4*)(Bp + (size_t)k0 * N + 4);
#pragma unroll
            for (int i = 0; i < 4; ++i) {
                Bs[bnn + i][bk]     = (bf16_t)b0[i];
                Bs[bnn + 4 + i][bk] = (bf16_t)b1[i];
            }
        }
        __syncthreads();

        bf16x8 af = *(const bf16x8*)(&As[wave * 16 + lr][quad * 8]);
#pragma unroll
        for (int nt = 0; nt < 4; ++nt) {
            bf16x8 bfrag = *(const bf16x8*)(&Bs[nt * 16 + lr][quad * 8]);
            acc[nt] = __builtin_amdgcn_mfma_f32_16x16x32_bf16(af, bfrag, acc[nt], 0, 0, 0);
        }
    }

    const int mb = bm0 + wave * 16 + quad * 4;
#pragma unroll
    for (int nt = 0; nt < 4; ++nt) {
        const int n = bn0 + nt * 16 + lr;
        const float bv = BIAS ? bias[n] : 0.f;
#pragma unroll
        for (int r = 0; r < 4; ++r) {
            const int m = mb + r;
            float v = acc[nt][r] + bv;
            if (RES)   v += res[(size_t)m * N + n];
            if (GELU_) v = 0.5f * v * (1.f + erff(v * 0.70710678118654752f));
            if (OUTF32) ((float*)Cp)[(size_t)m * N + n] = v;
            else        ((bf16_t*)Cp)[(size_t)m * N + n] = (bf16_t)v;
        }
    }
}

// ---------------- flash attention, MFMA (1 block per (b,h, 64-q tile)) ----------------
// qkv row layout (bf16): [b*T+t][0:768)=Q, [768:1536)=K, [1536:2304)=V; head h at h*64+d.
// 4 waves; wave w owns q rows q0+w*16 .. +15. K-tiles of 64 keys.
// Layouts (m89/m91/m120): A frag m=lane&15,k=quad*8+j; B frag n=lane&15,k=quad*8+j;
// C/D: row=quad*4+reg, col=lane&15. P goes C-layout -> LDS -> A-layout.
__global__ __launch_bounds__(256) void attn_kernel(
    const bf16_t* __restrict__ qkv, bf16_t* __restrict__ y)
{
    __shared__ bf16_t Ks[64][72];      // [key][dim]   (stride 72: 144B, 16B-aligned)
    __shared__ bf16_t Vt[64][72];      // [dim][key]   (transposed at stage-in)
    __shared__ bf16_t Ps[4][16][72];   // per-wave P tile [q][key]

    const int q0   = blockIdx.x * 64;
    const int bh   = blockIdx.y;             // h + H*b
    const int b    = bh / H_;
    const int hh   = bh % H_;
    const int t    = threadIdx.x;
    const int wave = t >> 6;
    const int lane = t & 63;
    const int lr   = lane & 15;
    const int quad = lane >> 4;

    // Q fragments (A-layout), resident for whole kernel
    const size_t qg = ((size_t)b * T_ + q0 + wave * 16 + lr) * (3 * D_) + hh * HD_;
    const bf16x8 aQ0 = *(const bf16x8*)(qkv + qg + quad * 8);
    const bf16x8 aQ1 = *(const bf16x8*)(qkv + qg + 32 + quad * 8);

    f32x4 o[4];
#pragma unroll
    for (int i = 0; i < 4; ++i) { f32x4 z = {0.f, 0.f, 0.f, 0.f}; o[i] = z; }
    float mrow[4] = {-1e30f, -1e30f, -1e30f, -1e30f};
    float lrow[4] = {0.f, 0.f, 0.f, 0.f};

    for (int kt = 0; kt <= (int)blockIdx.x; ++kt) {
        const int k_base = kt * 64;
        __syncthreads();   // previous iter's LDS reads done before restage

        // stage K tile: thread t -> key=t>>2, dim chunk (t&3)*8 and +32
        {
            const int key = t >> 2, dc = (t & 3) * 8;
            const size_t g = ((size_t)b * T_ + k_base + key) * (3 * D_) + D_ + hh * HD_;
            *(bf16x8*)(&Ks[key][dc])      = *(const bf16x8*)(qkv + g + dc);
            *(bf16x8*)(&Ks[key][dc + 32]) = *(const bf16x8*)(qkv + g + dc + 32);
        }
        // stage V transposed: thread t -> key=lane, dims wave*16..+15
        {
            const int key = lane;
            const size_t g = ((size_t)b * T_ + k_base + key) * (3 * D_) + 2 * D_ + hh * HD_ + wave * 16;
            const bf16x8 v0 = *(const bf16x8*)(qkv + g);
            const bf16x8 v1 = *(const bf16x8*)(qkv + g + 8);
#pragma unroll
            for (int i = 0; i < 8; ++i) {
                Vt[wave * 16 + i][key]     = v0[i];
                Vt[wave * 16 + 8 + i][key] = v1[i];
            }
        }
        __syncthreads();

        // QK^T: s[nt] = Q(16x64) . K^T -> 16x16 tiles, nt over 64 keys
        f32x4 s[4];
#pragma unroll
        for (int i = 0; i < 4; ++i) { f32x4 z = {0.f, 0.f, 0.f, 0.f}; s[i] = z; }
#pragma unroll
        for (int nt = 0; nt < 4; ++nt) {
            bf16x8 bk0 = *(const bf16x8*)(&Ks[nt * 16 + lr][quad * 8]);
            bf16x8 bk1 = *(const bf16x8*)(&Ks[nt * 16 + lr][32 + quad * 8]);
            s[nt] = __builtin_amdgcn_mfma_f32_16x16x32_bf16(aQ0, bk0, s[nt], 0, 0, 0);
            s[nt] = __builtin_amdgcn_mfma_f32_16x16x32_bf16(aQ1, bk1, s[nt], 0, 0, 0);
        }

        // online softmax, per row r (q = q0 + wave*16 + quad*4 + r)
#pragma unroll
        for (int r = 0; r < 4; ++r) {
            const int qg_i = q0 + wave * 16 + quad * 4 + r;
            float mx = -1e30f;
#pragma unroll
            for (int nt = 0; nt < 4; ++nt) {
                float sv = s[nt][r] * 0.125f;
                if (k_base + nt * 16 + lr > qg_i) sv = -1e30f;
                s[nt][r] = sv;
                mx = fmaxf(mx, sv);
            }
            mx = fmaxf(mx, __shfl_xor(mx, 1));
            mx = fmaxf(mx, __shfl_xor(mx, 2));
            mx = fmaxf(mx, __shfl_xor(mx, 4));
            mx = fmaxf(mx, __shfl_xor(mx, 8));
            const float mnew = fmaxf(mrow[r], mx);
            float ps = 0.f;
#pragma unroll
            for (int nt = 0; nt < 4; ++nt) {
                const float p = __expf(s[nt][r] - mnew);
                s[nt][r] = p;
                ps += p;
            }
            ps += __shfl_xor(ps, 1);
            ps += __shfl_xor(ps, 2);
            ps += __shfl_xor(ps, 4);
            ps += __shfl_xor(ps, 8);
            const float alpha = __expf(mrow[r] - mnew);
            lrow[r] = lrow[r] * alpha + ps;
            mrow[r] = mnew;
#pragma unroll
            for (int nt = 0; nt < 4; ++nt) o[nt][r] *= alpha;
        }

        // P: C-layout -> per-wave LDS tile (no barrier: same-wave producer/consumer)
#pragma unroll
        for (int nt = 0; nt < 4; ++nt)
#pragma unroll
            for (int r = 0; r < 4; ++r)
                Ps[wave][quad * 4 + r][nt * 16 + lr] = (bf16_t)s[nt][r];

        // PV: A = P (A-layout read), B = V^T tile
        const bf16x8 aP0 = *(const bf16x8*)(&Ps[wave][lr][quad * 8]);
        const bf16x8 aP1 = *(const bf16x8*)(&Ps[wave][lr][32 + quad * 8]);
#pragma unroll
        for (int nt = 0; nt < 4; ++nt) {
            bf16x8 bv0 = *(const bf16x8*)(&Vt[nt * 16 + lr][quad * 8]);
            bf16x8 bv1 = *(const bf16x8*)(&Vt[nt * 16 + lr][32 + quad * 8]);
            o[nt] = __builtin_amdgcn_mfma_f32_16x16x32_bf16(aP0, bv0, o[nt], 0, 0, 0);
            o[nt] = __builtin_amdgcn_mfma_f32_16x16x32_bf16(aP1, bv1, o[nt], 0, 0, 0);
        }
    }

    // epilogue: normalize and store (C-layout: row=quad*4+r, col=nt*16+lr)
#pragma unroll
    for (int r = 0; r < 4; ++r) {
        const float inv = 1.f / lrow[r];
        const size_t row = (size_t)b * T_ + q0 + wave * 16 + quad * 4 + r;
#pragma unroll
        for (int nt = 0; nt < 4; ++nt)
            y[row * D_ + hh * HD_ + nt * 16 + lr] = (bf16_t)(o[nt][r] * inv);
    }
}

// ---------------- launch ----------------
extern "C" void kernel_launch(void* const* d_in, const int* in_sizes, int n_in,
                              void* d_out, int out_size, void* d_ws, size_t ws_size,
                              hipStream_t stream)
{
    const int*   ids  = (const int*)d_in[0];
    const float* tok  = (const float*)d_in[1];
    const float* pos  = (const float*)d_in[2];
    const float* l1w  = (const float*)d_in[3];
    const float* l1b  = (const float*)d_in[4];
    const float* qkvw = (const float*)d_in[5];
    const float* outw = (const float*)d_in[6];
    const float* l2w  = (const float*)d_in[7];
    const float* l2b  = (const float*)d_in[8];
    const float* w1   = (const float*)d_in[9];
    const float* b1   = (const float*)d_in[10];
    const float* w2   = (const float*)d_in[11];
    const float* b2   = (const float*)d_in[12];
    const float* lnfw = (const float*)d_in[13];
    const float* lnfb = (const float*)d_in[14];

    float*  x   = (float*)d_ws;                         // [2048][768]  f32
    bf16_t* h   = (bf16_t*)(x + (size_t)M_ * D_);       // [2048][768]  bf16
    bf16_t* qkv = h   + (size_t)M_ * D_;                // [2048][2304] bf16
    bf16_t* y   = qkv + (size_t)M_ * 3 * D_;            // [2048][768]  bf16
    bf16_t* mid = y   + (size_t)M_ * D_;                // [2048][3072] bf16

    embed_kernel<<<M_, 256, 0, stream>>>(ids, tok, pos, x);

    for (int l = 0; l < L_; ++l) {
        ln_kernel<<<M_, 256, 0, stream>>>(x, l1w + l * D_, l1b + l * D_, h);
        gemm_kernel<false, false, false, false, false><<<dim3(3 * D_ / 64, M_ / 64), 256, 0, stream>>>(
            h, qkvw + (size_t)l * D_ * 3 * D_, nullptr, nullptr, qkv, M_, 3 * D_, D_);
        attn_kernel<<<dim3(T_ / 64, B_ * H_), 256, 0, stream>>>(qkv, y);
        gemm_kernel<false, true, false, false, true><<<dim3(D_ / 64, M_ / 64), 256, 0, stream>>>(
            y, outw + (size_t)l * D_ * D_, nullptr, x, x, M_, D_, D_);
        ln_kernel<<<M_, 256, 0, stream>>>(x, l2w + l * D_, l2b + l * D_, h);
        gemm_kernel<false, false, true, true, false><<<dim3(F_ / 64, M_ / 64), 256, 0, stream>>>(
            h, w1 + (size_t)l * D_ * F_, b1 + (size_t)l * F_, nullptr, mid, M_, F_, D_);
        gemm_kernel<false, true, true, false, true><<<dim3(D_ / 64, M_ / 64), 256, 0, stream>>>(
            mid, w2 + (size_t)l * F_ * D_, b2 + (size_t)l * D_, x, x, M_, D_, F_);
    }

    ln_kernel<<<M_, 256, 0, stream>>>(x, lnfw, lnfb, h);
    gemm_kernel<true, false, false, false, true><<<dim3(V_ / 64, M_ / 64), 256, 0, stream>>>(
        h, tok, nullptr, nullptr, d_out, M_, V_, D_);
}

// Round 4
// 1363.108 us; speedup vs baseline: 6.3164x; 1.6580x over previous
//
#include <hip/hip_runtime.h>
#include <hip/hip_bf16.h>
#include <math.h>

// ---- problem constants ----
#define D_  768
#define T_  1024
#define B_  2
#define H_  12
#define HD_ 64
#define L_  8
#define F_  3072
#define V_  1024
#define M_  (B_ * T_)   // 2048 rows of activations

typedef __bf16 bf16_t;
typedef __bf16 bf16x8 __attribute__((ext_vector_type(8)));
typedef float  f32x4  __attribute__((ext_vector_type(4)));

// async 16B global->LDS (direct DMA, lane i lands at lds_base + i*16)
__device__ __forceinline__ void ld_g2l16(const bf16_t* g, bf16_t* l)
{
    __builtin_amdgcn_global_load_lds(
        (const __attribute__((address_space(1))) void*)g,
        (__attribute__((address_space(3))) void*)l,
        16, 0, 0);
}

// ---------------- embed: x = tok_emb[ids] + pos_emb (all f32) ----------------
__global__ __launch_bounds__(256) void embed_kernel(
    const int* __restrict__ ids, const float* __restrict__ tok,
    const float* __restrict__ pos, float* __restrict__ x)
{
    const int row = blockIdx.x;          // b*T + t
    const int t   = row & (T_ - 1);
    const int id  = ids[row];
    const int c   = threadIdx.x;
#pragma unroll
    for (int i = 0; i < 3; ++i) {
        const int d = c + i * 256;
        x[(size_t)row * D_ + d] = tok[(size_t)id * D_ + d] + pos[(size_t)t * D_ + d];
    }
}

// ---------------- weight transpose+convert: f32 [K][N] -> bf16 [N][K] ----------------
__global__ __launch_bounds__(256) void wtrans_kernel(
    const float* __restrict__ in, bf16_t* __restrict__ out, int K, int N)
{
    __shared__ float tile[32][33];
    const int n0 = blockIdx.x * 32, k0 = blockIdx.y * 32;
    const int tx = threadIdx.x & 31, ty = threadIdx.x >> 5;   // ty 0..7
#pragma unroll
    for (int i = 0; i < 4; ++i)
        tile[ty + 8 * i][tx] = in[(size_t)(k0 + ty + 8 * i) * N + n0 + tx];
    __syncthreads();
#pragma unroll
    for (int i = 0; i < 4; ++i) {
        const int n = ty + 8 * i;
        out[(size_t)(n0 + n) * K + k0 + tx] = (bf16_t)tile[tx][n];
    }
}

// ---------------- straight convert f32 -> bf16 (tok_emb for lm_head) ----------------
__global__ __launch_bounds__(256) void conv_kernel(
    const float* __restrict__ in, bf16_t* __restrict__ out)
{
    const int i = blockIdx.x * 1024 + threadIdx.x * 4;
    const f32x4 v = *(const f32x4*)(in + i);
#pragma unroll
    for (int j = 0; j < 4; ++j) out[i + j] = (bf16_t)v[j];
}

// ---------------- layernorm: f32 in -> bf16 out ----------------
__device__ __forceinline__ float block_sum(float v)
{
    __shared__ float sm[4];
#pragma unroll
    for (int off = 32; off; off >>= 1) v += __shfl_down(v, off);
    if ((threadIdx.x & 63) == 0) sm[threadIdx.x >> 6] = v;
    __syncthreads();
    const float r = sm[0] + sm[1] + sm[2] + sm[3];
    __syncthreads();
    return r;
}

__global__ __launch_bounds__(256) void ln_kernel(
    const float* __restrict__ x, const float* __restrict__ w,
    const float* __restrict__ b, bf16_t* __restrict__ out)
{
    const int row = blockIdx.x;
    const float* xr = x + (size_t)row * D_;
    const int t = threadIdx.x;
    const float v0 = xr[t];
    const float v1 = xr[t + 256];
    const float v2 = xr[t + 512];
    const float mu = block_sum(v0 + v1 + v2) * (1.f / D_);
    const float d0 = v0 - mu, d1 = v1 - mu, d2 = v2 - mu;
    const float var = block_sum(d0 * d0 + d1 * d1 + d2 * d2) * (1.f / D_);
    const float rstd = rsqrtf(var + 1e-5f);
    bf16_t* o = out + (size_t)row * D_;
    o[t]       = (bf16_t)(d0 * rstd * w[t]       + b[t]);
    o[t + 256] = (bf16_t)(d1 * rstd * w[t + 256] + b[t + 256]);
    o[t + 512] = (bf16_t)(d2 * rstd * w[t + 512] + b[t + 512]);
}

// ---------------- GEMM (B^T bf16): C[M,N] = act(A[M,K] @ Bt[N,K]^T + bias + res) ----
// BM=64, BK=64, BN in {64,128}; 256 threads = 4 waves in 2x2 quadrants, each wave
// computes 32 x BN/2. Staging via global_load_lds width=16 into unpadded LDS with
// XOR-8 16B-chunk swizzle: row r's k-chunk c lives at chunk slot c^(r&7) -> fragment
// ds_read_b128 spreads over 8 bank groups (2-way = free, m136).
// MFMA layouts (m89/m91): A/B frag idx=lane&15, k=quad*8+j; D row=quad*4+reg, col=lane&15.
template<int BN, bool RES, bool BIAS, bool GELU_, bool OUTF32>
__global__ __launch_bounds__(256) void gemm_bt(
    const bf16_t* __restrict__ A, const bf16_t* __restrict__ Bt,
    const float* __restrict__ bias, const float* __restrict__ res,
    void* __restrict__ Cp, int M, int N, int K)
{
    constexpr int BM = 64, BK = 64;
    constexpr int WN = BN / 2, NT = WN / 16;
    constexpr int AR = (BM * BK) / (256 * 8);   // 2 staging rounds for A
    constexpr int BR = (BN * BK) / (256 * 8);   // 2 or 4 for B
    __shared__ bf16_t As[BM * BK];
    __shared__ bf16_t Bs[BN * BK];

    const int t    = threadIdx.x;
    const int wave = t >> 6, lane = t & 63;
    const int lr   = lane & 15, quad = lane >> 4;
    const int bm0  = blockIdx.y * BM, bn0 = blockIdx.x * BN;
    const int wm   = wave >> 1, wn = wave & 1;

    f32x4 acc[2][NT];
#pragma unroll
    for (int i = 0; i < 2; ++i)
#pragma unroll
        for (int j = 0; j < NT; ++j) { f32x4 z = {0.f, 0.f, 0.f, 0.f}; acc[i][j] = z; }

    // per-round staging source pointers (swizzled chunk choice per lane)
    const bf16_t* asrc[AR];
    const bf16_t* bsrc[BR];
#pragma unroll
    for (int rnd = 0; rnd < AR; ++rnd) {
        const int p = rnd * 256 + t, row = p >> 3, c = (p & 7) ^ (row & 7);
        asrc[rnd] = A + (size_t)(bm0 + row) * K + c * 8;
    }
#pragma unroll
    for (int rnd = 0; rnd < BR; ++rnd) {
        const int p = rnd * 256 + t, row = p >> 3, c = (p & 7) ^ (row & 7);
        bsrc[rnd] = Bt + (size_t)(bn0 + row) * K + c * 8;
    }

    for (int k0 = 0; k0 < K; k0 += BK) {
        __syncthreads();   // previous iter's LDS reads done
#pragma unroll
        for (int rnd = 0; rnd < AR; ++rnd)
            ld_g2l16(asrc[rnd] + k0, As + (rnd * 256 + wave * 64) * 8);
#pragma unroll
        for (int rnd = 0; rnd < BR; ++rnd)
            ld_g2l16(bsrc[rnd] + k0, Bs + (rnd * 256 + wave * 64) * 8);
        __syncthreads();   // compiler drains vmcnt before barrier -> data ready

#pragma unroll
        for (int ks = 0; ks < 2; ++ks) {
            const int ch = ((quad + 4 * ks) ^ (lr & 7)) * 8;
            const bf16x8 a0 = *(const bf16x8*)(As + (wm * 32 + lr) * BK + ch);
            const bf16x8 a1 = *(const bf16x8*)(As + (wm * 32 + 16 + lr) * BK + ch);
#pragma unroll
            for (int nt = 0; nt < NT; ++nt) {
                const bf16x8 b = *(const bf16x8*)(Bs + (wn * WN + nt * 16 + lr) * BK + ch);
                acc[0][nt] = __builtin_amdgcn_mfma_f32_16x16x32_bf16(a0, b, acc[0][nt], 0, 0, 0);
                acc[1][nt] = __builtin_amdgcn_mfma_f32_16x16x32_bf16(a1, b, acc[1][nt], 0, 0, 0);
            }
        }
    }

    // epilogue: D row=quad*4+r, col=lane&15
#pragma unroll
    for (int mt = 0; mt < 2; ++mt) {
        const int mbase = bm0 + wm * 32 + mt * 16 + quad * 4;
#pragma unroll
        for (int nt = 0; nt < NT; ++nt) {
            const int n = bn0 + wn * WN + nt * 16 + lr;
            const float bv = BIAS ? bias[n] : 0.f;
#pragma unroll
            for (int r = 0; r < 4; ++r) {
                const int m = mbase + r;
                float v = acc[mt][nt][r] + bv;
                if (RES)   v += res[(size_t)m * N + n];
                if (GELU_) v = 0.5f * v * (1.f + erff(v * 0.70710678118654752f));
                if (OUTF32) ((float*)Cp)[(size_t)m * N + n] = v;
                else        ((bf16_t*)Cp)[(size_t)m * N + n] = (bf16_t)v;
            }
        }
    }
}

// ---------------- flash attention, MFMA (unchanged from round 3 — passed) ----------
__global__ __launch_bounds__(256) void attn_kernel(
    const bf16_t* __restrict__ qkv, bf16_t* __restrict__ y)
{
    __shared__ bf16_t Ks[64][72];
    __shared__ bf16_t Vt[64][72];
    __shared__ bf16_t Ps[4][16][72];

    const int q0   = blockIdx.x * 64;
    const int bh   = blockIdx.y;
    const int b    = bh / H_;
    const int hh   = bh % H_;
    const int t    = threadIdx.x;
    const int wave = t >> 6;
    const int lane = t & 63;
    const int lr   = lane & 15;
    const int quad = lane >> 4;

    const size_t qg = ((size_t)b * T_ + q0 + wave * 16 + lr) * (3 * D_) + hh * HD_;
    const bf16x8 aQ0 = *(const bf16x8*)(qkv + qg + quad * 8);
    const bf16x8 aQ1 = *(const bf16x8*)(qkv + qg + 32 + quad * 8);

    f32x4 o[4];
#pragma unroll
    for (int i = 0; i < 4; ++i) { f32x4 z = {0.f, 0.f, 0.f, 0.f}; o[i] = z; }
    float mrow[4] = {-1e30f, -1e30f, -1e30f, -1e30f};
    float lrow[4] = {0.f, 0.f, 0.f, 0.f};

    for (int kt = 0; kt <= (int)blockIdx.x; ++kt) {
        const int k_base = kt * 64;
        __syncthreads();

        {
            const int key = t >> 2, dc = (t & 3) * 8;
            const size_t g = ((size_t)b * T_ + k_base + key) * (3 * D_) + D_ + hh * HD_;
            *(bf16x8*)(&Ks[key][dc])      = *(const bf16x8*)(qkv + g + dc);
            *(bf16x8*)(&Ks[key][dc + 32]) = *(const bf16x8*)(qkv + g + dc + 32);
        }
        {
            const int key = lane;
            const size_t g = ((size_t)b * T_ + k_base + key) * (3 * D_) + 2 * D_ + hh * HD_ + wave * 16;
            const bf16x8 v0 = *(const bf16x8*)(qkv + g);
            const bf16x8 v1 = *(const bf16x8*)(qkv + g + 8);
#pragma unroll
            for (int i = 0; i < 8; ++i) {
                Vt[wave * 16 + i][key]     = v0[i];
                Vt[wave * 16 + 8 + i][key] = v1[i];
            }
        }
        __syncthreads();

        f32x4 s[4];
#pragma unroll
        for (int i = 0; i < 4; ++i) { f32x4 z = {0.f, 0.f, 0.f, 0.f}; s[i] = z; }
#pragma unroll
        for (int nt = 0; nt < 4; ++nt) {
            bf16x8 bk0 = *(const bf16x8*)(&Ks[nt * 16 + lr][quad * 8]);
            bf16x8 bk1 = *(const bf16x8*)(&Ks[nt * 16 + lr][32 + quad * 8]);
            s[nt] = __builtin_amdgcn_mfma_f32_16x16x32_bf16(aQ0, bk0, s[nt], 0, 0, 0);
            s[nt] = __builtin_amdgcn_mfma_f32_16x16x32_bf16(aQ1, bk1, s[nt], 0, 0, 0);
        }

#pragma unroll
        for (int r = 0; r < 4; ++r) {
            const int qg_i = q0 + wave * 16 + quad * 4 + r;
            float mx = -1e30f;
#pragma unroll
            for (int nt = 0; nt < 4; ++nt) {
                float sv = s[nt][r] * 0.125f;
                if (k_base + nt * 16 + lr > qg_i) sv = -1e30f;
                s[nt][r] = sv;
                mx = fmaxf(mx, sv);
            }
            mx = fmaxf(mx, __shfl_xor(mx, 1));
            mx = fmaxf(mx, __shfl_xor(mx, 2));
            mx = fmaxf(mx, __shfl_xor(mx, 4));
            mx = fmaxf(mx, __shfl_xor(mx, 8));
            const float mnew = fmaxf(mrow[r], mx);
            float ps = 0.f;
#pragma unroll
            for (int nt = 0; nt < 4; ++nt) {
                const float p = __expf(s[nt][r] - mnew);
                s[nt][r] = p;
                ps += p;
            }
            ps += __shfl_xor(ps, 1);
            ps += __shfl_xor(ps, 2);
            ps += __shfl_xor(ps, 4);
            ps += __shfl_xor(ps, 8);
            const float alpha = __expf(mrow[r] - mnew);
            lrow[r] = lrow[r] * alpha + ps;
            mrow[r] = mnew;
#pragma unroll
            for (int nt = 0; nt < 4; ++nt) o[nt][r] *= alpha;
        }

#pragma unroll
        for (int nt = 0; nt < 4; ++nt)
#pragma unroll
            for (int r = 0; r < 4; ++r)
                Ps[wave][quad * 4 + r][nt * 16 + lr] = (bf16_t)s[nt][r];

        const bf16x8 aP0 = *(const bf16x8*)(&Ps[wave][lr][quad * 8]);
        const bf16x8 aP1 = *(const bf16x8*)(&Ps[wave][lr][32 + quad * 8]);
#pragma unroll
        for (int nt = 0; nt < 4; ++nt) {
            bf16x8 bv0 = *(const bf16x8*)(&Vt[nt * 16 + lr][quad * 8]);
            bf16x8 bv1 = *(const bf16x8*)(&Vt[nt * 16 + lr][32 + quad * 8]);
            o[nt] = __builtin_amdgcn_mfma_f32_16x16x32_bf16(aP0, bv0, o[nt], 0, 0, 0);
            o[nt] = __builtin_amdgcn_mfma_f32_16x16x32_bf16(aP1, bv1, o[nt], 0, 0, 0);
        }
    }

#pragma unroll
    for (int r = 0; r < 4; ++r) {
        const float inv = 1.f / lrow[r];
        const size_t row = (size_t)b * T_ + q0 + wave * 16 + quad * 4 + r;
#pragma unroll
        for (int nt = 0; nt < 4; ++nt)
            y[row * D_ + hh * HD_ + nt * 16 + lr] = (bf16_t)(o[nt][r] * inv);
    }
}

// ---------------- launch ----------------
extern "C" void kernel_launch(void* const* d_in, const int* in_sizes, int n_in,
                              void* d_out, int out_size, void* d_ws, size_t ws_size,
                              hipStream_t stream)
{
    const int*   ids  = (const int*)d_in[0];
    const float* tok  = (const float*)d_in[1];
    const float* pos  = (const float*)d_in[2];
    const float* l1w  = (const float*)d_in[3];
    const float* l1b  = (const float*)d_in[4];
    const float* qkvw = (const float*)d_in[5];
    const float* outw = (const float*)d_in[6];
    const float* l2w  = (const float*)d_in[7];
    const float* l2b  = (const float*)d_in[8];
    const float* w1   = (const float*)d_in[9];
    const float* b1   = (const float*)d_in[10];
    const float* w2   = (const float*)d_in[11];
    const float* b2   = (const float*)d_in[12];
    const float* lnfw = (const float*)d_in[13];
    const float* lnfb = (const float*)d_in[14];

    float*  x     = (float*)d_ws;                       // [2048][768]  f32
    bf16_t* h     = (bf16_t*)(x + (size_t)M_ * D_);     // [2048][768]
    bf16_t* qkv   = h     + (size_t)M_ * D_;            // [2048][2304]
    bf16_t* y     = qkv   + (size_t)M_ * 3 * D_;        // [2048][768]
    bf16_t* mid   = y     + (size_t)M_ * D_;            // [2048][3072]
    bf16_t* tokb  = mid   + (size_t)M_ * F_;            // [1024][768]
    bf16_t* wqkvT = tokb  + (size_t)V_ * D_;            // [2304][768]
    bf16_t* woutT = wqkvT + (size_t)3 * D_ * D_;        // [768][768]
    bf16_t* w1T   = woutT + (size_t)D_ * D_;            // [3072][768]
    bf16_t* w2T   = w1T   + (size_t)F_ * D_;            // [768][3072]

    embed_kernel<<<M_, 256, 0, stream>>>(ids, tok, pos, x);
    conv_kernel<<<(V_ * D_) / 1024, 256, 0, stream>>>(tok, tokb);

    for (int l = 0; l < L_; ++l) {
        wtrans_kernel<<<dim3(3 * D_ / 32, D_ / 32), 256, 0, stream>>>(
            qkvw + (size_t)l * D_ * 3 * D_, wqkvT, D_, 3 * D_);
        wtrans_kernel<<<dim3(D_ / 32, D_ / 32), 256, 0, stream>>>(
            outw + (size_t)l * D_ * D_, woutT, D_, D_);
        wtrans_kernel<<<dim3(F_ / 32, D_ / 32), 256, 0, stream>>>(
            w1 + (size_t)l * D_ * F_, w1T, D_, F_);
        wtrans_kernel<<<dim3(D_ / 32, F_ / 32), 256, 0, stream>>>(
            w2 + (size_t)l * F_ * D_, w2T, F_, D_);

        ln_kernel<<<M_, 256, 0, stream>>>(x, l1w + l * D_, l1b + l * D_, h);
        gemm_bt<128, false, false, false, false><<<dim3(3 * D_ / 128, M_ / 64), 256, 0, stream>>>(
            h, wqkvT, nullptr, nullptr, qkv, M_, 3 * D_, D_);
        attn_kernel<<<dim3(T_ / 64, B_ * H_), 256, 0, stream>>>(qkv, y);
        gemm_bt<64, true, false, false, true><<<dim3(D_ / 64, M_ / 64), 256, 0, stream>>>(
            y, woutT, nullptr, x, x, M_, D_, D_);
        ln_kernel<<<M_, 256, 0, stream>>>(x, l2w + l * D_, l2b + l * D_, h);
        gemm_bt<128, false, true, true, false><<<dim3(F_ / 128, M_ / 64), 256, 0, stream>>>(
            h, w1T, b1 + (size_t)l * F_, nullptr, mid, M_, F_, D_);
        gemm_bt<64, true, true, false, true><<<dim3(D_ / 64, M_ / 64), 256, 0, stream>>>(
            mid, w2T, b2 + (size_t)l * D_, x, x, M_, D_, F_);
    }

    ln_kernel<<<M_, 256, 0, stream>>>(x, lnfw, lnfb, h);
    gemm_bt<64, false, false, false, true><<<dim3(V_ / 64, M_ / 64), 256, 0, stream>>>(
        h, tokb, nullptr, nullptr, d_out, M_, V_, D_);
}